// Round 16
// baseline (354.421 us; speedup 1.0000x reference)
//
#include <hip/hip_runtime.h>
#include <math.h>

// HAN (2-layer) on MI355X.
// GEMMs: A bf16 image staged via global_load_lds (2-phase dbuf, 8-16KB LDS);
// W split-bf16 fragment-major swizzled image read DIRECTLY from L2 (no LDS --
// image is <=128KB, L2-resident; a wave's fragment read = 1KB contiguous).
// Transform GEMMs = 2 MFMA products + FUSED node-attention-score dots.
// Score GEMMs = 1 product (hi-only W) + fast tanh + wave-shuffle reduce.
// Aggregation: single-pass segment softmax (no max; logits bounded), inline
// edge logits, 32-lane group per dst node, unroll-4 with index prefetch,
// packed-f32 accumulate. Prologue fused. Layer-2: author-only work.

#define NA 20000
#define NP 30000
#define NE 200000
#define D1 256   // HID
#define D2 128   // OUT

typedef __attribute__((ext_vector_type(8))) short short8v;
typedef __attribute__((ext_vector_type(4))) float floatx4;
typedef __attribute__((ext_vector_type(2))) float float2v;
typedef __attribute__((ext_vector_type(8))) unsigned short ushort8v;
typedef __attribute__((ext_vector_type(4))) unsigned short ushort4v;

static __device__ __forceinline__ float lrelu(float x) { return x >= 0.f ? x : 0.2f * x; }

static __device__ __forceinline__ unsigned short bftrunc(float x) {
    return (unsigned short)(__float_as_uint(x) >> 16);
}
static __device__ __forceinline__ float bf2f(unsigned short b) {
    return __uint_as_float(((unsigned)b) << 16);
}
// round-to-nearest-even f32 -> bf16
static __device__ __forceinline__ unsigned short bfrn(float x) {
    unsigned u = __float_as_uint(x);
    return (unsigned short)((u + 0x7FFFu + ((u >> 16) & 1u)) >> 16);
}
// tanh(x) = 1 - 2/(exp(2x)+1); exact asymptotics, ~1e-6 rel error.
static __device__ __forceinline__ float fast_tanh(float x) {
    const float e = __expf(2.f * x);
    return 1.f - 2.f * __builtin_amdgcn_rcpf(e + 1.f);
}

typedef __attribute__((address_space(1))) const unsigned int as1_uint;
typedef __attribute__((address_space(3))) unsigned int as3_uint;
static __device__ __forceinline__ void gl_lds16(const void* g, void* l) {
    __builtin_amdgcn_global_load_lds((as1_uint*)g, (as3_uint*)l, 16, 0, 0);
}

static inline int cdiv(int a, int b) { return (a + b - 1) / b; }

// ================= fused prologue: W prep + x round + degree count =================
// blockIdx.y: 0..5 = w_prep matrix m; 6..7 = xround m-6; 8..11 = count_deg ty-8.
struct Prologue {
    const float* W[6];
    unsigned short* img[6];
    int N[6];
    int nsl[6];
    const float* x[2];
    unsigned short* xo[2];
    int xn8[2];
    const int* dstv[4];
    int* cnt[4];
};

__global__ __launch_bounds__(256) void prologue_k(Prologue p) {
    const int task = blockIdx.y;
    const int idx = blockIdx.x * 256 + threadIdx.x;
    if (task < 6) {
        const int m = task;
        if (idx >= p.nsl[m]) return;
        const int N = p.N[m];
        const int slot = idx & 3;
        const int col = (idx >> 2) % N;
        const int rest = (idx >> 2) / N;
        const int part = rest & 1;
        const int kt = rest >> 1;
        const int ks = slot ^ ((col >> 1) & 3);
        unsigned short* dst = p.img[m] + (((size_t)(kt * 2 + part) * N + col) * 32) + slot * 8;
        const float* wsrc = p.W[m] + (size_t)(kt * 32 + ks * 8) * N + col;
        short8v o;
#pragma unroll
        for (int k = 0; k < 8; ++k) {
            const float x = wsrc[(size_t)k * N];
            const unsigned short hb = bftrunc(x);
            o[k] = part ? (short)bftrunc(x - bf2f(hb)) : (short)hb;
        }
        *(short8v*)dst = o;
    } else if (task < 8) {
        const int m = task - 6;
        if (idx >= p.xn8[m]) return;
        const float* xp = p.x[m] + (size_t)idx * 8;
        float4 v0 = *(const float4*)xp;
        float4 v1 = *(const float4*)(xp + 4);
        const float xs8[8] = {v0.x, v0.y, v0.z, v0.w, v1.x, v1.y, v1.z, v1.w};
        short8v o;
#pragma unroll
        for (int k = 0; k < 8; ++k) o[k] = (short)bfrn(xs8[k]);
        *(short8v*)&p.xo[m][(size_t)idx * 8] = o;
    } else {
        const int ty = task - 8;
        if (idx < NE) atomicAdd(&p.cnt[ty][p.dstv[ty][idx]], 1);
    }
}

// ================= CSR fill =================
struct CsrBatch {
    const int* srcv[4];
    const int* dstv[4];
    int* cnt[4];
    int* csrc[4];
    int* cdst[4];
};

__global__ __launch_bounds__(256) void fill_csr_b(CsrBatch c, int n) {
    const int ty = blockIdx.y;
    const int i = blockIdx.x * 256 + threadIdx.x;
    if (i < n) {
        const int d = c.dstv[ty][i];
        const int p = atomicAdd(&c.cnt[ty][d], 1);
        c.csrc[ty][p] = c.srcv[ty][i];
        c.cdst[ty][p] = d;
    }
}

// 4 edge-type exclusive scans in one launch (blockIdx = type), wave-shuffle based.
__global__ __launch_bounds__(1024) void exscan4(int* __restrict__ curbase,
                                                int* __restrict__ rpbase) {
    const int off_c[4] = {0, NP, NP + NA, NP + NA + NP};
    const int off_r[4] = {0, NP + 1, NP + NA + 2, NP + NA + NP + 3};
    const int ns[4] = {NP, NA, NP, NA};
    const int b = blockIdx.x;
    int* cur = curbase + off_c[b];
    int* rp = rpbase + off_r[b];
    const int n = ns[b];
    __shared__ int wsum[16];
    __shared__ int carry_s;
    const int t = threadIdx.x, wv = t >> 6, ln = t & 63;
    if (t == 0) carry_s = 0;
    __syncthreads();
    for (int base = 0; base < n; base += 1024) {
        const int i = base + t;
        const int v = (i < n) ? cur[i] : 0;
        int x = v;
#pragma unroll
        for (int off = 1; off < 64; off <<= 1) {
            int y = __shfl_up(x, off);
            if (ln >= off) x += y;
        }
        if (ln == 63) wsum[wv] = x;
        __syncthreads();
        if (wv == 0) {
            int s = (ln < 16) ? wsum[ln] : 0;
#pragma unroll
            for (int off = 1; off < 16; off <<= 1) {
                int y = __shfl_up(s, off);
                if (ln >= off) s += y;
            }
            if (ln < 16) wsum[ln] = s;
        }
        __syncthreads();
        const int woff = (wv == 0) ? 0 : wsum[wv - 1];
        const int c = carry_s;
        const int ex = c + woff + x - v;
        if (i < n) { rp[i] = ex; cur[i] = ex; }
        __syncthreads();
        if (t == 1023) carry_s = c + wsum[15];
        __syncthreads();
    }
    if (t == 0) rp[n] = carry_s;
}

// ====== MFMA GEMM: A via LDS dbuf; W fragments read direct from L2 image ======
template <int NT>
struct GemmBatch {
    const unsigned short* A[NT];
    const unsigned short* Wimg[NT];
    const float* bias[NT];
    unsigned short* C[NT];
    int M[NT];
    const float* att[NT][4];
    float* sout[NT][4];
    int nsc[NT];
};

template <int BN, bool SCORE, bool SPLITW, bool NSF, int NT>
__global__ __launch_bounds__(256) void gemm_sw(
    GemmBatch<NT> g, const float* __restrict__ qv, float* __restrict__ score, int K) {
    constexpr int WGN = BN / 64;
    constexpr int WGM = 4 / WGN;
    constexpr int BM = WGM * 64;
    constexpr int ACH = BM * 64 / 1024;    // A 1KB chunks per k-tile (4 or 8)
    constexpr int APW = ACH / 4;           // chunks per wave (1 or 2)
    constexpr int ASZ = BM * 64;           // bytes per A buffer
    const int ty = blockIdx.y;
    const int M = g.M[ty];
    const int bm = blockIdx.x * BM;
    if (bm >= M) return;
    const unsigned short* __restrict__ A = g.A[ty];
    const unsigned short* __restrict__ Wi = g.Wimg[ty];
    const float* __restrict__ bias = g.bias[ty];
    __shared__ __attribute__((aligned(16))) unsigned short As[2][BM][32];
    const int t = threadIdx.x;
    const int lane = t & 63, wid = t >> 6;
    const int wr = wid / WGN, wc = wid % WGN;
    const int fq = lane >> 4, fr = lane & 15;
    const int asl = (fq ^ ((fr >> 1) & 3)) * 16;      // swizzled LDS read slot (bytes)
    const int asle = (fq ^ ((fr >> 1) & 3)) * 8;      // swizzled image slot (elems)
    const int lr = lane >> 2;
    const int lks = (lane & 3) ^ ((lane >> 3) & 3);
    floatx4 acc[4][4];
#pragma unroll
    for (int i = 0; i < 4; ++i)
#pragma unroll
        for (int j = 0; j < 4; ++j) acc[i][j] = {0.f, 0.f, 0.f, 0.f};

    const int NK = K >> 5;
    auto STAGE = [&](int b, int ki) {
#pragma unroll
        for (int ci = 0; ci < APW; ++ci) {
            const int c = wid * APW + ci;
            const int row = c * 16 + lr;
            const char* srcp = (const char*)(A + (size_t)(bm + row) * K + ki * 32 + lks * 8);
            gl_lds16(srcp, (char*)As + b * ASZ + c * 1024);
        }
    };
    STAGE(0, 0);
    __syncthreads();
    int cur = 0;
    for (int ki = 0; ki < NK; ++ki) {
        if (ki + 1 < NK) STAGE(cur ^ 1, ki + 1);
        const unsigned short* __restrict__ wk = Wi + (size_t)ki * (2 * BN * 32);
        short8v a[4], bh[4], bl[4];
#pragma unroll
        for (int f = 0; f < 4; ++f) {
            const int ar = wr * 64 + f * 16 + fr;
            a[f] = *(const short8v*)((const char*)As + cur * ASZ + ar * 64 + asl);
            const int bc = wc * 64 + f * 16 + fr;
            bh[f] = *(const short8v*)&wk[(size_t)bc * 32 + asle];
            if constexpr (SPLITW)
                bl[f] = *(const short8v*)&wk[((size_t)BN + bc) * 32 + asle];
        }
#pragma unroll
        for (int i = 0; i < 4; ++i)
#pragma unroll
            for (int j = 0; j < 4; ++j) {
                acc[i][j] = __builtin_amdgcn_mfma_f32_16x16x32_bf16(a[i], bh[j], acc[i][j], 0, 0, 0);
                if constexpr (SPLITW)
                    acc[i][j] = __builtin_amdgcn_mfma_f32_16x16x32_bf16(a[i], bl[j], acc[i][j], 0, 0, 0);
            }
        __syncthreads();   // drains A prefetch + protects buffer overwrite
        cur ^= 1;
    }
    if constexpr (!SCORE) {
        unsigned short* __restrict__ Cb = g.C[ty];
#pragma unroll
        for (int i = 0; i < 4; ++i) {
            const int gr0 = bm + wr * 64 + i * 16 + fq * 4;
#pragma unroll
            for (int j = 0; j < 4; ++j) {
                const int col = wc * 64 + j * 16 + fr;
                const float b = bias[col];
#pragma unroll
                for (int r = 0; r < 4; ++r) {
                    const int gr = gr0 + r;
                    if (gr < M) Cb[(size_t)gr * BN + col] = bfrn(acc[i][j][r] + b);
                }
            }
        }
        if constexpr (NSF) {
            // fused node-attention-score dots: s[n,h] = <h1[n,h,:], att[h,:]>.
            // BN=256: wave wc owns head wc. BN=128: wave wc owns heads 2wc,2wc+1.
            const int nscv = g.nsc[ty];
            float bj[4];
#pragma unroll
            for (int j = 0; j < 4; ++j) bj[j] = bias[wc * 64 + j * 16 + fr];
#pragma unroll
            for (int v = 0; v < 4; ++v) {
                if (v >= nscv) break;
                const float* __restrict__ av = g.att[ty][v];
                float* __restrict__ sv = g.sout[ty][v];
                float avj[4];
#pragma unroll
                for (int j = 0; j < 4; ++j) avj[j] = av[wc * 64 + j * 16 + fr];
#pragma unroll
                for (int i = 0; i < 4; ++i) {
#pragma unroll
                    for (int r = 0; r < 4; ++r) {
                        const int gr = bm + wr * 64 + i * 16 + fq * 4 + r;
                        if constexpr (BN == 256) {
                            float pr = 0.f;
#pragma unroll
                            for (int j = 0; j < 4; ++j)
                                pr += (acc[i][j][r] + bj[j]) * avj[j];
                            pr += __shfl_xor(pr, 1); pr += __shfl_xor(pr, 2);
                            pr += __shfl_xor(pr, 4); pr += __shfl_xor(pr, 8);
                            if (fr == 0 && gr < M) sv[gr * 4 + wc] = pr;
                        } else {
                            float p0 = (acc[i][0][r] + bj[0]) * avj[0]
                                     + (acc[i][1][r] + bj[1]) * avj[1];
                            float p1 = (acc[i][2][r] + bj[2]) * avj[2]
                                     + (acc[i][3][r] + bj[3]) * avj[3];
                            p0 += __shfl_xor(p0, 1); p0 += __shfl_xor(p0, 2);
                            p0 += __shfl_xor(p0, 4); p0 += __shfl_xor(p0, 8);
                            p1 += __shfl_xor(p1, 1); p1 += __shfl_xor(p1, 2);
                            p1 += __shfl_xor(p1, 4); p1 += __shfl_xor(p1, 8);
                            if (fr == 0 && gr < M) {
                                sv[gr * 4 + 2 * wc] = p0;
                                sv[gr * 4 + 2 * wc + 1] = p1;
                            }
                        }
                    }
                }
            }
        }
    } else {
        // wave-shuffle reduce + single barrier (no 256-wide LDS tree)
        __shared__ float redw[4];
        float partial = 0.f;
#pragma unroll
        for (int i = 0; i < 4; ++i) {
            const int gr0 = bm + wr * 64 + i * 16 + fq * 4;
#pragma unroll
            for (int j = 0; j < 4; ++j) {
                const int col = wc * 64 + j * 16 + fr;
                const float b = bias[col], q = qv[col];
#pragma unroll
                for (int r = 0; r < 4; ++r) {
                    if (gr0 + r < M) partial += fast_tanh(acc[i][j][r] + b) * q;
                }
            }
        }
#pragma unroll
        for (int off = 1; off < 64; off <<= 1) partial += __shfl_xor(partial, off);
        if (lane == 0) redw[wid] = partial;
        __syncthreads();
        if (t == 0) atomicAdd(&score[ty], redw[0] + redw[1] + redw[2] + redw[3]);
    }
}

// ==== single-pass segment softmax (no max; logits bounded) + inline edge logits ====
// packed-f32 accumulate (float2 vectors -> v_pk_fma_f32)
template <int EPL>
static __device__ __forceinline__ void accum(const unsigned short* p, float ea, float2v* acc2) {
    const float2v eav = {ea, ea};
    if constexpr (EPL >= 8) {
#pragma unroll
        for (int w = 0; w < EPL / 8; ++w) {
            ushort8v x = *(const ushort8v*)(p + w * 8);
#pragma unroll
            for (int k = 0; k < 4; ++k) {
                float2v xv = {bf2f(x[2 * k]), bf2f(x[2 * k + 1])};
                acc2[w * 4 + k] += xv * eav;
            }
        }
    } else {
        ushort4v x = *(const ushort4v*)p;
#pragma unroll
        for (int k = 0; k < 2; ++k) {
            float2v xv = {bf2f(x[2 * k]), bf2f(x[2 * k + 1])};
            acc2[k] += xv * eav;
        }
    }
}

template <int NT>
struct AggBatch {
    const unsigned short* xs[NT];
    const float* ss[NT];
    const float* sd[NT];
    const int* csrc[NT];
    const int* rowptr[NT];
    unsigned short* out[NT];
    int ndst[NT];
};

// 256 threads = 8 groups of 32 lanes; group -> one dst node; lane owns EPL=D/32.
// Unroll-4 main loop with next-quad index prefetch (hides L2 index latency).
template <int D, int NT>
__global__ __launch_bounds__(256) void agg_b(AggBatch<NT> a) {
    constexpr int EPL = D / 32;
    const int ty = blockIdx.y;
    const int gid = blockIdx.x * 8 + (threadIdx.x >> 5);
    if (gid >= a.ndst[ty]) return;
    const int g = threadIdx.x & 31;
    const int h = g >> 3;
    const int* __restrict__ rp = a.rowptr[ty];
    const int e0 = rp[gid], e1 = rp[gid + 1];
    const float* __restrict__ ss = a.ss[ty];
    const int* __restrict__ cs = a.csrc[ty];
    const unsigned short* __restrict__ xs = a.xs[ty];
    const float sdh = a.sd[ty][gid * 4 + h];
    float2v acc2[EPL / 2];
#pragma unroll
    for (int k = 0; k < EPL / 2; ++k) acc2[k] = {0.f, 0.f};
    float denom = 0.f;
    const int nq = (e1 - e0) >> 2;
    int e = e0;
    if (nq > 0) {
        int r0 = cs[e], r1 = cs[e + 1], r2 = cs[e + 2], r3 = cs[e + 3];
        for (int q = 0; q < nq; ++q) {
            int n0, n1, n2, n3;
            const bool more = (q + 1 < nq);
            if (more) {
                n0 = cs[e + 4]; n1 = cs[e + 5]; n2 = cs[e + 6]; n3 = cs[e + 7];
            }
            const float l0 = lrelu(ss[r0 * 4 + h] + sdh);
            const float l1 = lrelu(ss[r1 * 4 + h] + sdh);
            const float l2 = lrelu(ss[r2 * 4 + h] + sdh);
            const float l3 = lrelu(ss[r3 * 4 + h] + sdh);
            const float ea0 = __expf(l0), ea1 = __expf(l1);
            const float ea2 = __expf(l2), ea3 = __expf(l3);
            denom += (ea0 + ea1) + (ea2 + ea3);
            accum<EPL>(xs + (size_t)r0 * D + g * EPL, ea0, acc2);
            accum<EPL>(xs + (size_t)r1 * D + g * EPL, ea1, acc2);
            accum<EPL>(xs + (size_t)r2 * D + g * EPL, ea2, acc2);
            accum<EPL>(xs + (size_t)r3 * D + g * EPL, ea3, acc2);
            e += 4;
            if (more) { r0 = n0; r1 = n1; r2 = n2; r3 = n3; }
        }
    }
    for (; e < e1; ++e) {
        const int r0 = cs[e];
        const float l0 = lrelu(ss[r0 * 4 + h] + sdh);
        const float ea0 = __expf(l0);
        denom += ea0;
        accum<EPL>(xs + (size_t)r0 * D + g * EPL, ea0, acc2);
    }
    const float inv = 1.f / (denom + 1e-16f);
    unsigned short* __restrict__ orow = a.out[ty] + (size_t)gid * D + g * EPL;
    if constexpr (EPL >= 8) {
#pragma unroll
        for (int w = 0; w < EPL / 8; ++w) {
            short8v o;
#pragma unroll
            for (int k = 0; k < 4; ++k) {
                o[2 * k] = (short)bfrn(fmaxf(acc2[w * 4 + k][0] * inv, 0.f));
                o[2 * k + 1] = (short)bfrn(fmaxf(acc2[w * 4 + k][1] * inv, 0.f));
            }
            *(short8v*)&orow[w * 8] = o;
        }
    } else {
        ushort4v o;
#pragma unroll
        for (int k = 0; k < 2; ++k) {
            o[2 * k] = bfrn(fmaxf(acc2[k][0] * inv, 0.f));
            o[2 * k + 1] = bfrn(fmaxf(acc2[k][1] * inv, 0.f));
        }
        *(ushort4v*)orow = o;
    }
}

// ================= semantic softmax + combine (bf16 -> bf16), batched =================
struct CombBatch {
    const unsigned short* a[2];
    const unsigned short* b[2];
    unsigned short* o[2];
    int n8[2];
    int slot[2];
    float invN[2];
};

__global__ __launch_bounds__(256) void combine_b(CombBatch c, const float* __restrict__ sc) {
    const int ty = blockIdx.y;
    const int i = blockIdx.x * 256 + threadIdx.x;
    if (i >= c.n8[ty]) return;
    const float s0 = sc[c.slot[ty]] * c.invN[ty];
    const float s1 = sc[c.slot[ty] + 1] * c.invN[ty];
    const float m = fmaxf(s0, s1);
    const float e0 = expf(s0 - m), e1 = expf(s1 - m);
    const float w0 = e0 / (e0 + e1), w1 = e1 / (e0 + e1);
    const size_t o = (size_t)i * 8;
    ushort8v x = *(const ushort8v*)&c.a[ty][o];
    ushort8v y = *(const ushort8v*)&c.b[ty][o];
    short8v r;
#pragma unroll
    for (int k = 0; k < 8; ++k)
        r[k] = (short)bfrn(w0 * bf2f(x[k]) + w1 * bf2f(y[k]));
    *(short8v*)&c.o[ty][o] = r;
}

// final combine: bf16 pair -> f32 output
__global__ __launch_bounds__(256) void combine_out(
    const unsigned short* __restrict__ a, const unsigned short* __restrict__ b,
    float* __restrict__ out, const float* __restrict__ sc, int slot, float invN, int n8) {
    const int i = blockIdx.x * 256 + threadIdx.x;
    if (i >= n8) return;
    const float s0 = sc[slot] * invN, s1 = sc[slot + 1] * invN;
    const float m = fmaxf(s0, s1);
    const float e0 = expf(s0 - m), e1 = expf(s1 - m);
    const float w0 = e0 / (e0 + e1), w1 = e1 / (e0 + e1);
    const size_t o = (size_t)i * 8;
    ushort8v x = *(const ushort8v*)&a[o];
    ushort8v y = *(const ushort8v*)&b[o];
    float rr[8];
#pragma unroll
    for (int k = 0; k < 8; ++k) rr[k] = w0 * bf2f(x[k]) + w1 * bf2f(y[k]);
    float4 r0 = {rr[0], rr[1], rr[2], rr[3]};
    float4 r1 = {rr[4], rr[5], rr[6], rr[7]};
    *(float4*)&out[o] = r0;
    *(float4*)&out[o + 4] = r1;
}

extern "C" void kernel_launch(void* const* d_in, const int* in_sizes, int n_in,
                              void* d_out, int out_size, void* d_ws, size_t ws_size,
                              hipStream_t stream) {
    const float* x_a = (const float*)d_in[0];
    const float* x_p = (const float*)d_in[1];
    const int* src[4] = {(const int*)d_in[2], (const int*)d_in[4], (const int*)d_in[6], (const int*)d_in[8]};
    const int* dst[4] = {(const int*)d_in[3], (const int*)d_in[5], (const int*)d_in[7], (const int*)d_in[9]};
    const float* W1a = (const float*)d_in[10]; const float* b1a = (const float*)d_in[11];
    const float* W1p = (const float*)d_in[12]; const float* b1p = (const float*)d_in[13];
    const float* att1s = (const float*)d_in[14]; const float* att1d = (const float*)d_in[15];
    const float* q1 = (const float*)d_in[16];
    const float* k1W = (const float*)d_in[17]; const float* k1b = (const float*)d_in[18];
    const float* W2a = (const float*)d_in[19]; const float* b2a = (const float*)d_in[20];
    const float* W2p = (const float*)d_in[21]; const float* b2p = (const float*)d_in[22];
    const float* att2s = (const float*)d_in[23]; const float* att2d = (const float*)d_in[24];
    const float* q2 = (const float*)d_in[25];
    const float* k2W = (const float*)d_in[26]; const float* k2b = (const float*)d_in[27];

    const int NAp = NA + 128, NPp = NP + 128;
    char* wp = (char*)d_ws;
    unsigned short* xa_bf = (unsigned short*)wp; wp += (size_t)NAp * D1 * 2;
    unsigned short* xp_bf = (unsigned short*)wp; wp += (size_t)NPp * D1 * 2;
    unsigned short* h1a_bf = (unsigned short*)wp; wp += (size_t)NA * D1 * 2;
    unsigned short* h1p_bf = (unsigned short*)wp; wp += (size_t)NP * D1 * 2;
    unsigned short* a0 = (unsigned short*)wp; wp += (size_t)NPp * D1 * 2;
    unsigned short* a1 = (unsigned short*)wp; wp += (size_t)NAp * D1 * 2;
    unsigned short* a2 = (unsigned short*)wp; wp += (size_t)NPp * D1 * 2;
    unsigned short* a3 = (unsigned short*)wp; wp += (size_t)NAp * D1 * 2;
    float* sv = (float*)wp; wp += (size_t)(16 * NA + 16 * NP) * 4;
    int* rp_base = (int*)wp; wp += (size_t)(NP + NA + NP + NA + 4) * 4;
    int* cur_base = (int*)wp; wp += (size_t)(NP + NA + NP + NA) * 4;
    float* sc = (float*)wp; wp += 16 * 4;
    int* csrc_base = (int*)wp; wp += (size_t)4 * NE * 4;
    int* cdst_base = (int*)wp; wp += (size_t)4 * NE * 4;
    unsigned short* img_w1a = (unsigned short*)wp; wp += (size_t)8 * 2 * 256 * 32 * 2;
    unsigned short* img_w1p = (unsigned short*)wp; wp += (size_t)8 * 2 * 256 * 32 * 2;
    unsigned short* img_k1w = (unsigned short*)wp; wp += (size_t)8 * 2 * 256 * 32 * 2;
    unsigned short* img_w2a = (unsigned short*)wp; wp += (size_t)8 * 2 * 128 * 32 * 2;
    unsigned short* img_w2p = (unsigned short*)wp; wp += (size_t)8 * 2 * 128 * 32 * 2;
    unsigned short* img_k2w = (unsigned short*)wp; wp += (size_t)4 * 2 * 128 * 32 * 2;
    const size_t need_bytes = (size_t)(wp - (char*)d_ws);
    if (ws_size < need_bytes) return;

    int* rp[4] = {rp_base, rp_base + NP + 1, rp_base + NP + NA + 2, rp_base + NP + NA + NP + 3};
    int* cur[4] = {cur_base, cur_base + NP, cur_base + NP + NA, cur_base + NP + NA + NP};
    int* csrc[4]; int* cdst[4];
    for (int i = 0; i < 4; ++i) {
        csrc[i] = csrc_base + (size_t)i * NE;
        cdst[i] = cdst_base + (size_t)i * NE;
    }
    float* ss0 = sv;             float* sd0 = ss0 + NA * 4;
    float* ss1 = sd0 + NP * 4;   float* sd1 = ss1 + NP * 4;
    float* ss2 = sd1 + NA * 4;   float* sd2 = ss2 + NP * 4;
    float* ss3 = sd2 + NP * 4;   float* sd3 = ss3 + NA * 4;
    unsigned short* res_p = a0;
    unsigned short* res_a = a1;
    unsigned short* h2a_bf = a2;
    unsigned short* h2p_bf = a2 + (size_t)NA * D2;
    unsigned short* g21 = a3;
    unsigned short* g23 = a3 + (size_t)NAp * D2;
    float* ss21 = sv;             float* sd21 = ss21 + NP * 4;
    float* ss23 = sd21 + NA * 4;  float* sd23 = ss23 + NA * 4;

    hipMemsetAsync(cur_base, 0, (size_t)(NP + NA + NP + NA) * sizeof(int) + 16 * sizeof(float), stream);

    Prologue pl;
    const float* Ws[6] = {W1a, W1p, k1W, W2a, W2p, k2W};
    unsigned short* imgs[6] = {img_w1a, img_w1p, img_k1w, img_w2a, img_w2p, img_k2w};
    const int Ns[6] = {256, 256, 256, 128, 128, 128};
    const int nsls[6] = {8 * 2 * 256 * 4, 8 * 2 * 256 * 4, 8 * 2 * 256 * 4,
                         8 * 2 * 128 * 4, 8 * 2 * 128 * 4, 4 * 2 * 128 * 4};
    for (int i = 0; i < 6; ++i) { pl.W[i] = Ws[i]; pl.img[i] = imgs[i]; pl.N[i] = Ns[i]; pl.nsl[i] = nsls[i]; }
    pl.x[0] = x_a; pl.x[1] = x_p;
    pl.xo[0] = xa_bf; pl.xo[1] = xp_bf;
    pl.xn8[0] = NA * D1 / 8; pl.xn8[1] = NP * D1 / 8;
    for (int i = 0; i < 4; ++i) { pl.dstv[i] = dst[i]; pl.cnt[i] = cur[i]; }
    prologue_k<<<dim3(cdiv(NP * D1 / 8, 256), 12), 256, 0, stream>>>(pl);

    exscan4<<<4, 1024, 0, stream>>>(cur_base, rp_base);
    CsrBatch cb;
    for (int i = 0; i < 4; ++i) {
        cb.srcv[i] = src[i]; cb.dstv[i] = dst[i];
        cb.cnt[i] = cur[i]; cb.csrc[i] = csrc[i]; cb.cdst[i] = cdst[i];
    }
    fill_csr_b<<<dim3(cdiv(NE, 256), 4), 256, 0, stream>>>(cb, NE);

    // layer-1 transforms (split W, 64x256 blocks) + fused node-score dots
    GemmBatch<2> t1;
    t1.A[0] = xa_bf; t1.A[1] = xp_bf;
    t1.Wimg[0] = img_w1a; t1.Wimg[1] = img_w1p;
    t1.bias[0] = b1a; t1.bias[1] = b1p;
    t1.C[0] = h1a_bf; t1.C[1] = h1p_bf;
    t1.M[0] = NA; t1.M[1] = NP;
    t1.att[0][0] = att1s + 0 * 256; t1.att[0][1] = att1d + 1 * 256;
    t1.att[0][2] = att1s + 3 * 256; t1.att[0][3] = att1d + 3 * 256;
    t1.att[1][0] = att1d + 0 * 256; t1.att[1][1] = att1s + 1 * 256;
    t1.att[1][2] = att1s + 2 * 256; t1.att[1][3] = att1d + 2 * 256;
    t1.sout[0][0] = ss0; t1.sout[0][1] = sd1; t1.sout[0][2] = ss3; t1.sout[0][3] = sd3;
    t1.sout[1][0] = sd0; t1.sout[1][1] = ss1; t1.sout[1][2] = ss2; t1.sout[1][3] = sd2;
    t1.nsc[0] = 4; t1.nsc[1] = 4;
    gemm_sw<256, false, true, true, 2><<<dim3(cdiv(NP, 64), 2), 256, 0, stream>>>(t1, nullptr, nullptr, 256);

    // layer-1 aggregation (single-pass, inline logits, 32-lane groups, prefetch)
    AggBatch<4> ab1 = {{h1a_bf, h1p_bf, h1p_bf, h1a_bf},
                       {ss0, ss1, ss2, ss3}, {sd0, sd1, sd2, sd3},
                       {csrc[0], csrc[1], csrc[2], csrc[3]},
                       {rp[0], rp[1], rp[2], rp[3]},
                       {a0, a1, a2, a3},
                       {NP, NA, NP, NA}};
    agg_b<256, 4><<<dim3(cdiv(NP, 8), 4), 256, 0, stream>>>(ab1);

    // layer-1 semantic scores (hi-only W, fast tanh) + combine
    GemmBatch<4> s1;
    s1.A[0] = a0; s1.A[1] = a2; s1.A[2] = a1; s1.A[3] = a3;
    s1.Wimg[0] = s1.Wimg[1] = s1.Wimg[2] = s1.Wimg[3] = img_k1w;
    s1.bias[0] = s1.bias[1] = s1.bias[2] = s1.bias[3] = k1b;
    s1.C[0] = s1.C[1] = s1.C[2] = s1.C[3] = nullptr;
    s1.M[0] = NP; s1.M[1] = NP; s1.M[2] = NA; s1.M[3] = NA;
    s1.nsc[0] = s1.nsc[1] = s1.nsc[2] = s1.nsc[3] = 0;
    gemm_sw<256, true, false, false, 4><<<dim3(cdiv(NP, 64), 4), 256, 0, stream>>>(s1, q1, sc, 256);
    CombBatch c1 = {{a0, a1}, {a2, a3}, {res_p, res_a},
                    {NP * D1 / 8, NA * D1 / 8}, {0, 2}, {1.f / NP, 1.f / NA}};
    combine_b<<<dim3(cdiv(NP * D1 / 8, 256), 2), 256, 0, stream>>>(c1, sc);

    // layer-2 transforms (split W, 128x128 blocks) + fused node-score dots
    GemmBatch<2> t2;
    t2.A[0] = res_a; t2.A[1] = res_p;
    t2.Wimg[0] = img_w2a; t2.Wimg[1] = img_w2p;
    t2.bias[0] = b2a; t2.bias[1] = b2p;
    t2.C[0] = h2a_bf; t2.C[1] = h2p_bf;
    t2.M[0] = NA; t2.M[1] = NP;
    t2.att[0][0] = att2d + 1 * 128; t2.att[0][1] = att2s + 3 * 128;
    t2.att[0][2] = att2d + 3 * 128; t2.att[0][3] = nullptr;
    t2.att[1][0] = att2s + 1 * 128; t2.att[1][1] = nullptr;
    t2.att[1][2] = nullptr; t2.att[1][3] = nullptr;
    t2.sout[0][0] = sd21; t2.sout[0][1] = ss23; t2.sout[0][2] = sd23; t2.sout[0][3] = nullptr;
    t2.sout[1][0] = ss21; t2.sout[1][1] = nullptr; t2.sout[1][2] = nullptr; t2.sout[1][3] = nullptr;
    t2.nsc[0] = 3; t2.nsc[1] = 1;
    gemm_sw<128, false, true, true, 2><<<dim3(cdiv(NP, 128), 2), 256, 0, stream>>>(t2, nullptr, nullptr, 256);

    // layer-2 aggregation (author only: edge types 1 p->a, 3 a->a)
    AggBatch<2> ab2 = {{h2p_bf, h2a_bf},
                       {ss21, ss23}, {sd21, sd23},
                       {csrc[1], csrc[3]}, {rp[1], rp[3]},
                       {g21, g23}, {NA, NA}};
    agg_b<128, 2><<<dim3(cdiv(NA, 8), 2), 256, 0, stream>>>(ab2);

    // layer-2 semantic scores (hi-only W, fast tanh) -> output
    GemmBatch<2> s2;
    s2.A[0] = g21; s2.A[1] = g23;
    s2.Wimg[0] = s2.Wimg[1] = img_k2w;
    s2.bias[0] = s2.bias[1] = k2b;
    s2.C[0] = s2.C[1] = nullptr;
    s2.M[0] = NA; s2.M[1] = NA;
    s2.nsc[0] = s2.nsc[1] = 0;
    gemm_sw<128, true, false, false, 2><<<dim3(cdiv(NA, 128), 2), 256, 0, stream>>>(s2, q2, sc + 4, 128);
    combine_out<<<cdiv(NA * D2 / 8, 256), 256, 0, stream>>>(
        g21, g23, (float*)d_out, sc, 4, 1.f / NA, NA * D2 / 8);
}

// Round 17
// 350.054 us; speedup vs baseline: 1.0125x; 1.0125x over previous
//
#include <hip/hip_runtime.h>
#include <math.h>

// HAN (2-layer) on MI355X.  (R15 configuration -- best measured.)
// GEMMs: A bf16 image, W split-bf16 hi/lo fragment-major swizzled image.
// BN=256 -> 64x256 block (4 waves 1x4); BN=128 -> 128x128 (2x2); 2-phase
// double-buffered gl_lds staging, conflict-free swizzled ds_read_b128.
// Transform GEMMs = 2 MFMA products + FUSED node-attention-score dots.
// Score GEMMs = 1 product (hi-only W) + fast tanh + wave-shuffle reduce.
// Aggregation: single-pass segment softmax (no max; logits bounded), inline
// edge logits, 32-lane group per dst node, unroll-4 with index prefetch,
// packed-f32 accumulate. Prologue fused. Layer-2: author-only work.

#define NA 20000
#define NP 30000
#define NE 200000
#define D1 256   // HID
#define D2 128   // OUT

typedef __attribute__((ext_vector_type(8))) short short8v;
typedef __attribute__((ext_vector_type(4))) float floatx4;
typedef __attribute__((ext_vector_type(2))) float float2v;
typedef __attribute__((ext_vector_type(8))) unsigned short ushort8v;
typedef __attribute__((ext_vector_type(4))) unsigned short ushort4v;

static __device__ __forceinline__ float lrelu(float x) { return x >= 0.f ? x : 0.2f * x; }

static __device__ __forceinline__ unsigned short bftrunc(float x) {
    return (unsigned short)(__float_as_uint(x) >> 16);
}
static __device__ __forceinline__ float bf2f(unsigned short b) {
    return __uint_as_float(((unsigned)b) << 16);
}
// round-to-nearest-even f32 -> bf16
static __device__ __forceinline__ unsigned short bfrn(float x) {
    unsigned u = __float_as_uint(x);
    return (unsigned short)((u + 0x7FFFu + ((u >> 16) & 1u)) >> 16);
}
// tanh(x) = 1 - 2/(exp(2x)+1); exact asymptotics, ~1e-6 rel error.
static __device__ __forceinline__ float fast_tanh(float x) {
    const float e = __expf(2.f * x);
    return 1.f - 2.f * __builtin_amdgcn_rcpf(e + 1.f);
}

typedef __attribute__((address_space(1))) const unsigned int as1_uint;
typedef __attribute__((address_space(3))) unsigned int as3_uint;
static __device__ __forceinline__ void gl_lds16(const void* g, void* l) {
    __builtin_amdgcn_global_load_lds((as1_uint*)g, (as3_uint*)l, 16, 0, 0);
}

static inline int cdiv(int a, int b) { return (a + b - 1) / b; }

// ================= fused prologue: W prep + x round + degree count =================
// blockIdx.y: 0..5 = w_prep matrix m; 6..7 = xround m-6; 8..11 = count_deg ty-8.
struct Prologue {
    const float* W[6];
    unsigned short* img[6];
    int N[6];
    int nsl[6];
    const float* x[2];
    unsigned short* xo[2];
    int xn8[2];
    const int* dstv[4];
    int* cnt[4];
};

__global__ __launch_bounds__(256) void prologue_k(Prologue p) {
    const int task = blockIdx.y;
    const int idx = blockIdx.x * 256 + threadIdx.x;
    if (task < 6) {
        const int m = task;
        if (idx >= p.nsl[m]) return;
        const int N = p.N[m];
        const int slot = idx & 3;
        const int col = (idx >> 2) % N;
        const int rest = (idx >> 2) / N;
        const int part = rest & 1;
        const int kt = rest >> 1;
        const int ks = slot ^ ((col >> 1) & 3);
        unsigned short* dst = p.img[m] + (((size_t)(kt * 2 + part) * N + col) * 32) + slot * 8;
        const float* wsrc = p.W[m] + (size_t)(kt * 32 + ks * 8) * N + col;
        short8v o;
#pragma unroll
        for (int k = 0; k < 8; ++k) {
            const float x = wsrc[(size_t)k * N];
            const unsigned short hb = bftrunc(x);
            o[k] = part ? (short)bftrunc(x - bf2f(hb)) : (short)hb;
        }
        *(short8v*)dst = o;
    } else if (task < 8) {
        const int m = task - 6;
        if (idx >= p.xn8[m]) return;
        const float* xp = p.x[m] + (size_t)idx * 8;
        float4 v0 = *(const float4*)xp;
        float4 v1 = *(const float4*)(xp + 4);
        const float xs8[8] = {v0.x, v0.y, v0.z, v0.w, v1.x, v1.y, v1.z, v1.w};
        short8v o;
#pragma unroll
        for (int k = 0; k < 8; ++k) o[k] = (short)bfrn(xs8[k]);
        *(short8v*)&p.xo[m][(size_t)idx * 8] = o;
    } else {
        const int ty = task - 8;
        if (idx < NE) atomicAdd(&p.cnt[ty][p.dstv[ty][idx]], 1);
    }
}

// ================= CSR fill =================
struct CsrBatch {
    const int* srcv[4];
    const int* dstv[4];
    int* cnt[4];
    int* csrc[4];
    int* cdst[4];
};

__global__ __launch_bounds__(256) void fill_csr_b(CsrBatch c, int n) {
    const int ty = blockIdx.y;
    const int i = blockIdx.x * 256 + threadIdx.x;
    if (i < n) {
        const int d = c.dstv[ty][i];
        const int p = atomicAdd(&c.cnt[ty][d], 1);
        c.csrc[ty][p] = c.srcv[ty][i];
        c.cdst[ty][p] = d;
    }
}

// 4 edge-type exclusive scans in one launch (blockIdx = type), wave-shuffle based.
__global__ __launch_bounds__(1024) void exscan4(int* __restrict__ curbase,
                                                int* __restrict__ rpbase) {
    const int off_c[4] = {0, NP, NP + NA, NP + NA + NP};
    const int off_r[4] = {0, NP + 1, NP + NA + 2, NP + NA + NP + 3};
    const int ns[4] = {NP, NA, NP, NA};
    const int b = blockIdx.x;
    int* cur = curbase + off_c[b];
    int* rp = rpbase + off_r[b];
    const int n = ns[b];
    __shared__ int wsum[16];
    __shared__ int carry_s;
    const int t = threadIdx.x, wv = t >> 6, ln = t & 63;
    if (t == 0) carry_s = 0;
    __syncthreads();
    for (int base = 0; base < n; base += 1024) {
        const int i = base + t;
        const int v = (i < n) ? cur[i] : 0;
        int x = v;
#pragma unroll
        for (int off = 1; off < 64; off <<= 1) {
            int y = __shfl_up(x, off);
            if (ln >= off) x += y;
        }
        if (ln == 63) wsum[wv] = x;
        __syncthreads();
        if (wv == 0) {
            int s = (ln < 16) ? wsum[ln] : 0;
#pragma unroll
            for (int off = 1; off < 16; off <<= 1) {
                int y = __shfl_up(s, off);
                if (ln >= off) s += y;
            }
            if (ln < 16) wsum[ln] = s;
        }
        __syncthreads();
        const int woff = (wv == 0) ? 0 : wsum[wv - 1];
        const int c = carry_s;
        const int ex = c + woff + x - v;
        if (i < n) { rp[i] = ex; cur[i] = ex; }
        __syncthreads();
        if (t == 1023) carry_s = c + wsum[15];
        __syncthreads();
    }
    if (t == 0) rp[n] = carry_s;
}

// ====== MFMA GEMM: A bf16 image, W split image; 2-phase dbuf; optional fused ns ======
template <int NT>
struct GemmBatch {
    const unsigned short* A[NT];
    const unsigned short* Wimg[NT];
    const float* bias[NT];
    unsigned short* C[NT];
    int M[NT];
    const float* att[NT][4];
    float* sout[NT][4];
    int nsc[NT];
};

template <int BN, bool SCORE, bool SPLITW, bool NSF, int NT>
__global__ __launch_bounds__(256) void gemm_sw(
    GemmBatch<NT> g, const float* __restrict__ qv, float* __restrict__ score, int K) {
    constexpr int WGN = BN / 64;
    constexpr int WGM = 4 / WGN;
    constexpr int BM = WGM * 64;
    constexpr int NB = SPLITW ? 2 : 1;
    constexpr int ACH = BM * 32 * 2 / 1024;
    constexpr int BCH = NB * BN * 32 * 2 / 1024;
    constexpr int CPW = (ACH + BCH) / 4;
    constexpr int ASZ = BM * 64;
    constexpr int BSZ = NB * BN * 64;
    const int ty = blockIdx.y;
    const int M = g.M[ty];
    const int bm = blockIdx.x * BM;
    if (bm >= M) return;
    const unsigned short* __restrict__ A = g.A[ty];
    const unsigned short* __restrict__ Wi = g.Wimg[ty];
    const float* __restrict__ bias = g.bias[ty];
    __shared__ __attribute__((aligned(16))) unsigned short As[2][BM][32];
    __shared__ __attribute__((aligned(16))) unsigned short Bs[2][NB][BN][32];
    const int t = threadIdx.x;
    const int lane = t & 63, wid = t >> 6;
    const int wr = wid / WGN, wc = wid % WGN;
    const int fq = lane >> 4, fr = lane & 15;
    const int asl = (fq ^ ((fr >> 1) & 3)) * 16;
    const int lr = lane >> 2;
    const int lks = (lane & 3) ^ ((lane >> 3) & 3);
    floatx4 acc[4][4];
#pragma unroll
    for (int i = 0; i < 4; ++i)
#pragma unroll
        for (int j = 0; j < 4; ++j) acc[i][j] = {0.f, 0.f, 0.f, 0.f};

    const int NK = K >> 5;
    auto STAGE = [&](int b, int ki) {
        const char* wbase = (const char*)Wi + (size_t)ki * (2 * BN * 64);
#pragma unroll
        for (int ci = 0; ci < CPW; ++ci) {
            const int c = wid * CPW + ci;
            if (c < ACH) {
                const int row = c * 16 + lr;
                const char* srcp = (const char*)(A + (size_t)(bm + row) * K + ki * 32 + lks * 8);
                gl_lds16(srcp, (char*)As + b * ASZ + c * 1024);
            } else {
                const int bc = c - ACH;
                gl_lds16(wbase + (size_t)bc * 1024 + lane * 16, (char*)Bs + b * BSZ + bc * 1024);
            }
        }
    };
    STAGE(0, 0);
    __syncthreads();
    int cur = 0;
    for (int ki = 0; ki < NK; ++ki) {
        if (ki + 1 < NK) STAGE(cur ^ 1, ki + 1);
        short8v a[4], bh[4], bl[4];
#pragma unroll
        for (int f = 0; f < 4; ++f) {
            const int ar = wr * 64 + f * 16 + fr;
            a[f] = *(const short8v*)((const char*)As + cur * ASZ + ar * 64 + asl);
            const int bc = wc * 64 + f * 16 + fr;
            bh[f] = *(const short8v*)((const char*)Bs + cur * BSZ + bc * 64 + asl);
            if constexpr (SPLITW)
                bl[f] = *(const short8v*)((const char*)Bs + cur * BSZ + (size_t)BN * 64 + bc * 64 + asl);
        }
#pragma unroll
        for (int i = 0; i < 4; ++i)
#pragma unroll
            for (int j = 0; j < 4; ++j) {
                acc[i][j] = __builtin_amdgcn_mfma_f32_16x16x32_bf16(a[i], bh[j], acc[i][j], 0, 0, 0);
                if constexpr (SPLITW)
                    acc[i][j] = __builtin_amdgcn_mfma_f32_16x16x32_bf16(a[i], bl[j], acc[i][j], 0, 0, 0);
            }
        __syncthreads();
        cur ^= 1;
    }
    if constexpr (!SCORE) {
        unsigned short* __restrict__ Cb = g.C[ty];
#pragma unroll
        for (int i = 0; i < 4; ++i) {
            const int gr0 = bm + wr * 64 + i * 16 + fq * 4;
#pragma unroll
            for (int j = 0; j < 4; ++j) {
                const int col = wc * 64 + j * 16 + fr;
                const float b = bias[col];
#pragma unroll
                for (int r = 0; r < 4; ++r) {
                    const int gr = gr0 + r;
                    if (gr < M) Cb[(size_t)gr * BN + col] = bfrn(acc[i][j][r] + b);
                }
            }
        }
        if constexpr (NSF) {
            // fused node-attention-score dots: s[n,h] = <h1[n,h,:], att[h,:]>.
            // BN=256: wave wc owns head wc. BN=128: wave wc owns heads 2wc,2wc+1.
            const int nscv = g.nsc[ty];
            float bj[4];
#pragma unroll
            for (int j = 0; j < 4; ++j) bj[j] = bias[wc * 64 + j * 16 + fr];
#pragma unroll
            for (int v = 0; v < 4; ++v) {
                if (v >= nscv) break;
                const float* __restrict__ av = g.att[ty][v];
                float* __restrict__ sv = g.sout[ty][v];
                float avj[4];
#pragma unroll
                for (int j = 0; j < 4; ++j) avj[j] = av[wc * 64 + j * 16 + fr];
#pragma unroll
                for (int i = 0; i < 4; ++i) {
#pragma unroll
                    for (int r = 0; r < 4; ++r) {
                        const int gr = bm + wr * 64 + i * 16 + fq * 4 + r;
                        if constexpr (BN == 256) {
                            float pr = 0.f;
#pragma unroll
                            for (int j = 0; j < 4; ++j)
                                pr += (acc[i][j][r] + bj[j]) * avj[j];
                            pr += __shfl_xor(pr, 1); pr += __shfl_xor(pr, 2);
                            pr += __shfl_xor(pr, 4); pr += __shfl_xor(pr, 8);
                            if (fr == 0 && gr < M) sv[gr * 4 + wc] = pr;
                        } else {
                            float p0 = (acc[i][0][r] + bj[0]) * avj[0]
                                     + (acc[i][1][r] + bj[1]) * avj[1];
                            float p1 = (acc[i][2][r] + bj[2]) * avj[2]
                                     + (acc[i][3][r] + bj[3]) * avj[3];
                            p0 += __shfl_xor(p0, 1); p0 += __shfl_xor(p0, 2);
                            p0 += __shfl_xor(p0, 4); p0 += __shfl_xor(p0, 8);
                            p1 += __shfl_xor(p1, 1); p1 += __shfl_xor(p1, 2);
                            p1 += __shfl_xor(p1, 4); p1 += __shfl_xor(p1, 8);
                            if (fr == 0 && gr < M) {
                                sv[gr * 4 + 2 * wc] = p0;
                                sv[gr * 4 + 2 * wc + 1] = p1;
                            }
                        }
                    }
                }
            }
        }
    } else {
        // wave-shuffle reduce + single barrier (no 256-wide LDS tree)
        __shared__ float redw[4];
        float partial = 0.f;
#pragma unroll
        for (int i = 0; i < 4; ++i) {
            const int gr0 = bm + wr * 64 + i * 16 + fq * 4;
#pragma unroll
            for (int j = 0; j < 4; ++j) {
                const int col = wc * 64 + j * 16 + fr;
                const float b = bias[col], q = qv[col];
#pragma unroll
                for (int r = 0; r < 4; ++r) {
                    if (gr0 + r < M) partial += fast_tanh(acc[i][j][r] + b) * q;
                }
            }
        }
#pragma unroll
        for (int off = 1; off < 64; off <<= 1) partial += __shfl_xor(partial, off);
        if (lane == 0) redw[wid] = partial;
        __syncthreads();
        if (t == 0) atomicAdd(&score[ty], redw[0] + redw[1] + redw[2] + redw[3]);
    }
}

// ==== single-pass segment softmax (no max; logits bounded) + inline edge logits ====
// packed-f32 accumulate (float2 vectors -> v_pk_fma_f32)
template <int EPL>
static __device__ __forceinline__ void accum(const unsigned short* p, float ea, float2v* acc2) {
    const float2v eav = {ea, ea};
    if constexpr (EPL >= 8) {
#pragma unroll
        for (int w = 0; w < EPL / 8; ++w) {
            ushort8v x = *(const ushort8v*)(p + w * 8);
#pragma unroll
            for (int k = 0; k < 4; ++k) {
                float2v xv = {bf2f(x[2 * k]), bf2f(x[2 * k + 1])};
                acc2[w * 4 + k] += xv * eav;
            }
        }
    } else {
        ushort4v x = *(const ushort4v*)p;
#pragma unroll
        for (int k = 0; k < 2; ++k) {
            float2v xv = {bf2f(x[2 * k]), bf2f(x[2 * k + 1])};
            acc2[k] += xv * eav;
        }
    }
}

template <int NT>
struct AggBatch {
    const unsigned short* xs[NT];
    const float* ss[NT];
    const float* sd[NT];
    const int* csrc[NT];
    const int* rowptr[NT];
    unsigned short* out[NT];
    int ndst[NT];
};

// 256 threads = 8 groups of 32 lanes; group -> one dst node; lane owns EPL=D/32.
// Unroll-4 main loop with next-quad index prefetch (hides L2 index latency).
template <int D, int NT>
__global__ __launch_bounds__(256) void agg_b(AggBatch<NT> a) {
    constexpr int EPL = D / 32;
    const int ty = blockIdx.y;
    const int gid = blockIdx.x * 8 + (threadIdx.x >> 5);
    if (gid >= a.ndst[ty]) return;
    const int g = threadIdx.x & 31;
    const int h = g >> 3;
    const int* __restrict__ rp = a.rowptr[ty];
    const int e0 = rp[gid], e1 = rp[gid + 1];
    const float* __restrict__ ss = a.ss[ty];
    const int* __restrict__ cs = a.csrc[ty];
    const unsigned short* __restrict__ xs = a.xs[ty];
    const float sdh = a.sd[ty][gid * 4 + h];
    float2v acc2[EPL / 2];
#pragma unroll
    for (int k = 0; k < EPL / 2; ++k) acc2[k] = {0.f, 0.f};
    float denom = 0.f;
    const int nq = (e1 - e0) >> 2;
    int e = e0;
    if (nq > 0) {
        int r0 = cs[e], r1 = cs[e + 1], r2 = cs[e + 2], r3 = cs[e + 3];
        for (int q = 0; q < nq; ++q) {
            int n0, n1, n2, n3;
            const bool more = (q + 1 < nq);
            if (more) {
                n0 = cs[e + 4]; n1 = cs[e + 5]; n2 = cs[e + 6]; n3 = cs[e + 7];
            }
            const float l0 = lrelu(ss[r0 * 4 + h] + sdh);
            const float l1 = lrelu(ss[r1 * 4 + h] + sdh);
            const float l2 = lrelu(ss[r2 * 4 + h] + sdh);
            const float l3 = lrelu(ss[r3 * 4 + h] + sdh);
            const float ea0 = __expf(l0), ea1 = __expf(l1);
            const float ea2 = __expf(l2), ea3 = __expf(l3);
            denom += (ea0 + ea1) + (ea2 + ea3);
            accum<EPL>(xs + (size_t)r0 * D + g * EPL, ea0, acc2);
            accum<EPL>(xs + (size_t)r1 * D + g * EPL, ea1, acc2);
            accum<EPL>(xs + (size_t)r2 * D + g * EPL, ea2, acc2);
            accum<EPL>(xs + (size_t)r3 * D + g * EPL, ea3, acc2);
            e += 4;
            if (more) { r0 = n0; r1 = n1; r2 = n2; r3 = n3; }
        }
    }
    for (; e < e1; ++e) {
        const int r0 = cs[e];
        const float l0 = lrelu(ss[r0 * 4 + h] + sdh);
        const float ea0 = __expf(l0);
        denom += ea0;
        accum<EPL>(xs + (size_t)r0 * D + g * EPL, ea0, acc2);
    }
    const float inv = 1.f / (denom + 1e-16f);
    unsigned short* __restrict__ orow = a.out[ty] + (size_t)gid * D + g * EPL;
    if constexpr (EPL >= 8) {
#pragma unroll
        for (int w = 0; w < EPL / 8; ++w) {
            short8v o;
#pragma unroll
            for (int k = 0; k < 4; ++k) {
                o[2 * k] = (short)bfrn(fmaxf(acc2[w * 4 + k][0] * inv, 0.f));
                o[2 * k + 1] = (short)bfrn(fmaxf(acc2[w * 4 + k][1] * inv, 0.f));
            }
            *(short8v*)&orow[w * 8] = o;
        }
    } else {
        ushort4v o;
#pragma unroll
        for (int k = 0; k < 2; ++k) {
            o[2 * k] = bfrn(fmaxf(acc2[k][0] * inv, 0.f));
            o[2 * k + 1] = bfrn(fmaxf(acc2[k][1] * inv, 0.f));
        }
        *(ushort4v*)orow = o;
    }
}

// ================= semantic softmax + combine (bf16 -> bf16), batched =================
struct CombBatch {
    const unsigned short* a[2];
    const unsigned short* b[2];
    unsigned short* o[2];
    int n8[2];
    int slot[2];
    float invN[2];
};

__global__ __launch_bounds__(256) void combine_b(CombBatch c, const float* __restrict__ sc) {
    const int ty = blockIdx.y;
    const int i = blockIdx.x * 256 + threadIdx.x;
    if (i >= c.n8[ty]) return;
    const float s0 = sc[c.slot[ty]] * c.invN[ty];
    const float s1 = sc[c.slot[ty] + 1] * c.invN[ty];
    const float m = fmaxf(s0, s1);
    const float e0 = expf(s0 - m), e1 = expf(s1 - m);
    const float w0 = e0 / (e0 + e1), w1 = e1 / (e0 + e1);
    const size_t o = (size_t)i * 8;
    ushort8v x = *(const ushort8v*)&c.a[ty][o];
    ushort8v y = *(const ushort8v*)&c.b[ty][o];
    short8v r;
#pragma unroll
    for (int k = 0; k < 8; ++k)
        r[k] = (short)bfrn(w0 * bf2f(x[k]) + w1 * bf2f(y[k]));
    *(short8v*)&c.o[ty][o] = r;
}

// final combine: bf16 pair -> f32 output
__global__ __launch_bounds__(256) void combine_out(
    const unsigned short* __restrict__ a, const unsigned short* __restrict__ b,
    float* __restrict__ out, const float* __restrict__ sc, int slot, float invN, int n8) {
    const int i = blockIdx.x * 256 + threadIdx.x;
    if (i >= n8) return;
    const float s0 = sc[slot] * invN, s1 = sc[slot + 1] * invN;
    const float m = fmaxf(s0, s1);
    const float e0 = expf(s0 - m), e1 = expf(s1 - m);
    const float w0 = e0 / (e0 + e1), w1 = e1 / (e0 + e1);
    const size_t o = (size_t)i * 8;
    ushort8v x = *(const ushort8v*)&a[o];
    ushort8v y = *(const ushort8v*)&b[o];
    float rr[8];
#pragma unroll
    for (int k = 0; k < 8; ++k) rr[k] = w0 * bf2f(x[k]) + w1 * bf2f(y[k]);
    float4 r0 = {rr[0], rr[1], rr[2], rr[3]};
    float4 r1 = {rr[4], rr[5], rr[6], rr[7]};
    *(float4*)&out[o] = r0;
    *(float4*)&out[o + 4] = r1;
}

extern "C" void kernel_launch(void* const* d_in, const int* in_sizes, int n_in,
                              void* d_out, int out_size, void* d_ws, size_t ws_size,
                              hipStream_t stream) {
    const float* x_a = (const float*)d_in[0];
    const float* x_p = (const float*)d_in[1];
    const int* src[4] = {(const int*)d_in[2], (const int*)d_in[4], (const int*)d_in[6], (const int*)d_in[8]};
    const int* dst[4] = {(const int*)d_in[3], (const int*)d_in[5], (const int*)d_in[7], (const int*)d_in[9]};
    const float* W1a = (const float*)d_in[10]; const float* b1a = (const float*)d_in[11];
    const float* W1p = (const float*)d_in[12]; const float* b1p = (const float*)d_in[13];
    const float* att1s = (const float*)d_in[14]; const float* att1d = (const float*)d_in[15];
    const float* q1 = (const float*)d_in[16];
    const float* k1W = (const float*)d_in[17]; const float* k1b = (const float*)d_in[18];
    const float* W2a = (const float*)d_in[19]; const float* b2a = (const float*)d_in[20];
    const float* W2p = (const float*)d_in[21]; const float* b2p = (const float*)d_in[22];
    const float* att2s = (const float*)d_in[23]; const float* att2d = (const float*)d_in[24];
    const float* q2 = (const float*)d_in[25];
    const float* k2W = (const float*)d_in[26]; const float* k2b = (const float*)d_in[27];

    const int NAp = NA + 128, NPp = NP + 128;
    char* wp = (char*)d_ws;
    unsigned short* xa_bf = (unsigned short*)wp; wp += (size_t)NAp * D1 * 2;
    unsigned short* xp_bf = (unsigned short*)wp; wp += (size_t)NPp * D1 * 2;
    unsigned short* h1a_bf = (unsigned short*)wp; wp += (size_t)NA * D1 * 2;
    unsigned short* h1p_bf = (unsigned short*)wp; wp += (size_t)NP * D1 * 2;
    unsigned short* a0 = (unsigned short*)wp; wp += (size_t)NPp * D1 * 2;
    unsigned short* a1 = (unsigned short*)wp; wp += (size_t)NAp * D1 * 2;
    unsigned short* a2 = (unsigned short*)wp; wp += (size_t)NPp * D1 * 2;
    unsigned short* a3 = (unsigned short*)wp; wp += (size_t)NAp * D1 * 2;
    float* sv = (float*)wp; wp += (size_t)(16 * NA + 16 * NP) * 4;
    int* rp_base = (int*)wp; wp += (size_t)(NP + NA + NP + NA + 4) * 4;
    int* cur_base = (int*)wp; wp += (size_t)(NP + NA + NP + NA) * 4;
    float* sc = (float*)wp; wp += 16 * 4;
    int* csrc_base = (int*)wp; wp += (size_t)4 * NE * 4;
    int* cdst_base = (int*)wp; wp += (size_t)4 * NE * 4;
    unsigned short* img_w1a = (unsigned short*)wp; wp += (size_t)8 * 2 * 256 * 32 * 2;
    unsigned short* img_w1p = (unsigned short*)wp; wp += (size_t)8 * 2 * 256 * 32 * 2;
    unsigned short* img_k1w = (unsigned short*)wp; wp += (size_t)8 * 2 * 256 * 32 * 2;
    unsigned short* img_w2a = (unsigned short*)wp; wp += (size_t)8 * 2 * 128 * 32 * 2;
    unsigned short* img_w2p = (unsigned short*)wp; wp += (size_t)8 * 2 * 128 * 32 * 2;
    unsigned short* img_k2w = (unsigned short*)wp; wp += (size_t)4 * 2 * 128 * 32 * 2;
    const size_t need_bytes = (size_t)(wp - (char*)d_ws);
    if (ws_size < need_bytes) return;

    int* rp[4] = {rp_base, rp_base + NP + 1, rp_base + NP + NA + 2, rp_base + NP + NA + NP + 3};
    int* cur[4] = {cur_base, cur_base + NP, cur_base + NP + NA, cur_base + NP + NA + NP};
    int* csrc[4]; int* cdst[4];
    for (int i = 0; i < 4; ++i) {
        csrc[i] = csrc_base + (size_t)i * NE;
        cdst[i] = cdst_base + (size_t)i * NE;
    }
    float* ss0 = sv;             float* sd0 = ss0 + NA * 4;
    float* ss1 = sd0 + NP * 4;   float* sd1 = ss1 + NP * 4;
    float* ss2 = sd1 + NA * 4;   float* sd2 = ss2 + NP * 4;
    float* ss3 = sd2 + NP * 4;   float* sd3 = ss3 + NA * 4;
    unsigned short* res_p = a0;
    unsigned short* res_a = a1;
    unsigned short* h2a_bf = a2;
    unsigned short* h2p_bf = a2 + (size_t)NA * D2;
    unsigned short* g21 = a3;
    unsigned short* g23 = a3 + (size_t)NAp * D2;
    float* ss21 = sv;             float* sd21 = ss21 + NP * 4;
    float* ss23 = sd21 + NA * 4;  float* sd23 = ss23 + NA * 4;

    hipMemsetAsync(cur_base, 0, (size_t)(NP + NA + NP + NA) * sizeof(int) + 16 * sizeof(float), stream);

    Prologue pl;
    const float* Ws[6] = {W1a, W1p, k1W, W2a, W2p, k2W};
    unsigned short* imgs[6] = {img_w1a, img_w1p, img_k1w, img_w2a, img_w2p, img_k2w};
    const int Ns[6] = {256, 256, 256, 128, 128, 128};
    const int nsls[6] = {8 * 2 * 256 * 4, 8 * 2 * 256 * 4, 8 * 2 * 256 * 4,
                         8 * 2 * 128 * 4, 8 * 2 * 128 * 4, 4 * 2 * 128 * 4};
    for (int i = 0; i < 6; ++i) { pl.W[i] = Ws[i]; pl.img[i] = imgs[i]; pl.N[i] = Ns[i]; pl.nsl[i] = nsls[i]; }
    pl.x[0] = x_a; pl.x[1] = x_p;
    pl.xo[0] = xa_bf; pl.xo[1] = xp_bf;
    pl.xn8[0] = NA * D1 / 8; pl.xn8[1] = NP * D1 / 8;
    for (int i = 0; i < 4; ++i) { pl.dstv[i] = dst[i]; pl.cnt[i] = cur[i]; }
    prologue_k<<<dim3(cdiv(NP * D1 / 8, 256), 12), 256, 0, stream>>>(pl);

    exscan4<<<4, 1024, 0, stream>>>(cur_base, rp_base);
    CsrBatch cb;
    for (int i = 0; i < 4; ++i) {
        cb.srcv[i] = src[i]; cb.dstv[i] = dst[i];
        cb.cnt[i] = cur[i]; cb.csrc[i] = csrc[i]; cb.cdst[i] = cdst[i];
    }
    fill_csr_b<<<dim3(cdiv(NE, 256), 4), 256, 0, stream>>>(cb, NE);

    // layer-1 transforms (split W, 64x256 blocks) + fused node-score dots
    GemmBatch<2> t1;
    t1.A[0] = xa_bf; t1.A[1] = xp_bf;
    t1.Wimg[0] = img_w1a; t1.Wimg[1] = img_w1p;
    t1.bias[0] = b1a; t1.bias[1] = b1p;
    t1.C[0] = h1a_bf; t1.C[1] = h1p_bf;
    t1.M[0] = NA; t1.M[1] = NP;
    t1.att[0][0] = att1s + 0 * 256; t1.att[0][1] = att1d + 1 * 256;
    t1.att[0][2] = att1s + 3 * 256; t1.att[0][3] = att1d + 3 * 256;
    t1.att[1][0] = att1d + 0 * 256; t1.att[1][1] = att1s + 1 * 256;
    t1.att[1][2] = att1s + 2 * 256; t1.att[1][3] = att1d + 2 * 256;
    t1.sout[0][0] = ss0; t1.sout[0][1] = sd1; t1.sout[0][2] = ss3; t1.sout[0][3] = sd3;
    t1.sout[1][0] = sd0; t1.sout[1][1] = ss1; t1.sout[1][2] = ss2; t1.sout[1][3] = sd2;
    t1.nsc[0] = 4; t1.nsc[1] = 4;
    gemm_sw<256, false, true, true, 2><<<dim3(cdiv(NP, 64), 2), 256, 0, stream>>>(t1, nullptr, nullptr, 256);

    // layer-1 aggregation (single-pass, inline logits, 32-lane groups, prefetch)
    AggBatch<4> ab1 = {{h1a_bf, h1p_bf, h1p_bf, h1a_bf},
                       {ss0, ss1, ss2, ss3}, {sd0, sd1, sd2, sd3},
                       {csrc[0], csrc[1], csrc[2], csrc[3]},
                       {rp[0], rp[1], rp[2], rp[3]},
                       {a0, a1, a2, a3},
                       {NP, NA, NP, NA}};
    agg_b<256, 4><<<dim3(cdiv(NP, 8), 4), 256, 0, stream>>>(ab1);

    // layer-1 semantic scores (hi-only W, fast tanh) + combine
    GemmBatch<4> s1;
    s1.A[0] = a0; s1.A[1] = a2; s1.A[2] = a1; s1.A[3] = a3;
    s1.Wimg[0] = s1.Wimg[1] = s1.Wimg[2] = s1.Wimg[3] = img_k1w;
    s1.bias[0] = s1.bias[1] = s1.bias[2] = s1.bias[3] = k1b;
    s1.C[0] = s1.C[1] = s1.C[2] = s1.C[3] = nullptr;
    s1.M[0] = NP; s1.M[1] = NP; s1.M[2] = NA; s1.M[3] = NA;
    s1.nsc[0] = s1.nsc[1] = s1.nsc[2] = s1.nsc[3] = 0;
    gemm_sw<256, true, false, false, 4><<<dim3(cdiv(NP, 64), 4), 256, 0, stream>>>(s1, q1, sc, 256);
    CombBatch c1 = {{a0, a1}, {a2, a3}, {res_p, res_a},
                    {NP * D1 / 8, NA * D1 / 8}, {0, 2}, {1.f / NP, 1.f / NA}};
    combine_b<<<dim3(cdiv(NP * D1 / 8, 256), 2), 256, 0, stream>>>(c1, sc);

    // layer-2 transforms (split W, 128x128 blocks) + fused node-score dots
    GemmBatch<2> t2;
    t2.A[0] = res_a; t2.A[1] = res_p;
    t2.Wimg[0] = img_w2a; t2.Wimg[1] = img_w2p;
    t2.bias[0] = b2a; t2.bias[1] = b2p;
    t2.C[0] = h2a_bf; t2.C[1] = h2p_bf;
    t2.M[0] = NA; t2.M[1] = NP;
    t2.att[0][0] = att2d + 1 * 128; t2.att[0][1] = att2s + 3 * 128;
    t2.att[0][2] = att2d + 3 * 128; t2.att[0][3] = nullptr;
    t2.att[1][0] = att2s + 1 * 128; t2.att[1][1] = nullptr;
    t2.att[1][2] = nullptr; t2.att[1][3] = nullptr;
    t2.sout[0][0] = sd21; t2.sout[0][1] = ss23; t2.sout[0][2] = sd23; t2.sout[0][3] = nullptr;
    t2.sout[1][0] = ss21; t2.sout[1][1] = nullptr; t2.sout[1][2] = nullptr; t2.sout[1][3] = nullptr;
    t2.nsc[0] = 3; t2.nsc[1] = 1;
    gemm_sw<128, false, true, true, 2><<<dim3(cdiv(NP, 128), 2), 256, 0, stream>>>(t2, nullptr, nullptr, 256);

    // layer-2 aggregation (author only: edge types 1 p->a, 3 a->a)
    AggBatch<2> ab2 = {{h2p_bf, h2a_bf},
                       {ss21, ss23}, {sd21, sd23},
                       {csrc[1], csrc[3]}, {rp[1], rp[3]},
                       {g21, g23}, {NA, NA}};
    agg_b<128, 2><<<dim3(cdiv(NA, 8), 2), 256, 0, stream>>>(ab2);

    // layer-2 semantic scores (hi-only W, fast tanh) -> output
    GemmBatch<2> s2;
    s2.A[0] = g21; s2.A[1] = g23;
    s2.Wimg[0] = s2.Wimg[1] = img_k2w;
    s2.bias[0] = s2.bias[1] = k2b;
    s2.C[0] = s2.C[1] = nullptr;
    s2.M[0] = NA; s2.M[1] = NA;
    s2.nsc[0] = s2.nsc[1] = 0;
    gemm_sw<128, true, false, false, 2><<<dim3(cdiv(NA, 128), 2), 256, 0, stream>>>(s2, q2, sc + 4, 128);
    combine_out<<<cdiv(NA * D2 / 8, 256), 256, 0, stream>>>(
        g21, g23, (float*)d_out, sc, 4, 1.f / NA, NA * D2 / 8);
}